// Round 2
// baseline (51.534 us; speedup 1.0000x reference)
//
#include <hip/hip_runtime.h>
#include <math.h>

// YOLO-style loss: fused single-pass streaming reduction, 2 cells/thread for ILP.
// cells = N*S*S = 8192*169; pred row = 16 f32 (64B, line-aligned); tgt row = 13 f32 (52B, 4B-aligned only).

#define EPSV 1e-6f

struct CellIn {
    float4 p03; float p4, p9, p10, p11, p12;
    float t0, t1, t2, t3, t4, t10, t11, t12;
};

__device__ __forceinline__ void load_cell(const float* __restrict__ pred,
                                          const float* __restrict__ tgt,
                                          long long i, CellIn& c) {
    const float* pr = pred + i * 16;
    const float* tr = tgt  + i * 13;
    c.p03 = *reinterpret_cast<const float4*>(pr);
    c.p4  = pr[4];
    c.p9  = pr[9];
    float2 p1011 = *reinterpret_cast<const float2*>(pr + 10);
    c.p10 = p1011.x; c.p11 = p1011.y;
    c.p12 = pr[12];
    c.t0 = tr[0]; c.t1 = tr[1]; c.t2 = tr[2]; c.t3 = tr[3]; c.t4 = tr[4];
    c.t10 = tr[10]; c.t11 = tr[11]; c.t12 = tr[12];
}

__device__ __forceinline__ void accum_cell(const CellIn& c, float& accA, float& accB, float& accC) {
    float m = (c.t4 > 0.f) ? 1.f : 0.f;

    // coord
    float px = 1.f / (1.f + __expf(-c.p03.x));
    float py = 1.f / (1.f + __expf(-c.p03.y));
    float dx = px - c.t0;
    float dy = py - c.t1;
    float dw = sqrtf(fabsf(c.p03.z) + EPSV) - sqrtf(fabsf(c.t2) + EPSV);
    float dh = sqrtf(fabsf(c.p03.w) + EPSV) - sqrtf(fabsf(c.t3) + EPSV);
    float coord = dx*dx + dy*dy + dw*dw + dh*dh;

    // conf ch4: share log1p(exp(-|z|)) term; log1p(x) ~ __logf(1+x), x in (0,1]
    float l1p4 = __logf(1.f + __expf(-fabsf(c.p4)));
    float logsig_p4 = fminf(c.p4, 0.f) - l1p4;
    float logsig_m4 = fminf(-c.p4, 0.f) - l1p4;
    float bce_obj = -(c.t4 * logsig_p4 + (1.f - c.t4) * logsig_m4);
    float bce_no4 = -logsig_m4;
    float bce_no9 = fmaxf(c.p9, 0.f) + __logf(1.f + __expf(-fabsf(c.p9)));

    // class CE (first-max argmax of one-hot, stable LSE)
    int tcls = 0; float bt = c.t10;
    if (c.t11 > bt) { bt = c.t11; tcls = 1; }
    if (c.t12 > bt) { tcls = 2; }
    float lt = (tcls == 0) ? c.p10 : ((tcls == 1) ? c.p11 : c.p12);
    float mx = fmaxf(c.p10, fmaxf(c.p11, c.p12));
    float lse = mx + __logf(__expf(c.p10 - mx) + __expf(c.p11 - mx) + __expf(c.p12 - mx));
    float ce = lse - lt;

    accA += m * (5.f * coord + bce_obj + ce);
    accB += (1.f - m) * (bce_no4 + bce_no9);
    accC += m;
}

__global__ __launch_bounds__(256) void phobia_partial(
    const float* __restrict__ pred, const float* __restrict__ tgt,
    float* __restrict__ ws, long long cells, long long half)
{
    long long idx0 = (long long)blockIdx.x * blockDim.x + threadIdx.x;
    long long stride = (long long)gridDim.x * blockDim.x;

    float accA = 0.f, accB = 0.f, accC = 0.f;

    for (long long i = idx0; i < half; i += stride) {
        long long j = i + half;
        CellIn c0, c1;
        bool have1 = (j < cells);
        load_cell(pred, tgt, i, c0);
        if (have1) load_cell(pred, tgt, j, c1);   // independent load stream (ILP)
        accum_cell(c0, accA, accB, accC);
        if (have1) accum_cell(c1, accA, accB, accC);
    }

    #pragma unroll
    for (int o = 32; o > 0; o >>= 1) {
        accA += __shfl_down(accA, o, 64);
        accB += __shfl_down(accB, o, 64);
        accC += __shfl_down(accC, o, 64);
    }
    __shared__ float sA[4], sB[4], sC[4];
    int wave = threadIdx.x >> 6;
    int lane = threadIdx.x & 63;
    if (lane == 0) { sA[wave] = accA; sB[wave] = accB; sC[wave] = accC; }
    __syncthreads();
    if (threadIdx.x == 0) {
        ws[blockIdx.x * 3 + 0] = sA[0] + sA[1] + sA[2] + sA[3];
        ws[blockIdx.x * 3 + 1] = sB[0] + sB[1] + sB[2] + sB[3];
        ws[blockIdx.x * 3 + 2] = sC[0] + sC[1] + sC[2] + sC[3];
    }
}

__global__ __launch_bounds__(1024) void phobia_final(
    const float* __restrict__ ws, int nblocks, float* __restrict__ out, long long cells)
{
    float a = 0.f, b = 0.f, c = 0.f;
    for (int i = threadIdx.x; i < nblocks; i += 1024) {
        a += ws[i * 3 + 0];
        b += ws[i * 3 + 1];
        c += ws[i * 3 + 2];
    }
    #pragma unroll
    for (int o = 32; o > 0; o >>= 1) {
        a += __shfl_down(a, o, 64);
        b += __shfl_down(b, o, 64);
        c += __shfl_down(c, o, 64);
    }
    __shared__ float sA[16], sB[16], sC[16];
    int wave = threadIdx.x >> 6;
    int lane = threadIdx.x & 63;
    if (lane == 0) { sA[wave] = a; sB[wave] = b; sC[wave] = c; }
    __syncthreads();
    if (threadIdx.x == 0) {
        float A = 0.f, B = 0.f, C = 0.f;
        #pragma unroll
        for (int w = 0; w < 16; ++w) { A += sA[w]; B += sB[w]; C += sC[w]; }
        float batch = (float)(cells / 169);               // N
        float invb = 1.f / batch;
        float div_obj   = (C > 0.f) ? invb : 1.f;
        float div_noobj = (C < (float)cells) ? invb : 1.f;
        out[0] = A * div_obj + 0.5f * B * div_noobj;
    }
}

extern "C" void kernel_launch(void* const* d_in, const int* in_sizes, int n_in,
                              void* d_out, int out_size, void* d_ws, size_t ws_size,
                              hipStream_t stream) {
    const float* pred = (const float*)d_in[0];
    const float* tgt  = (const float*)d_in[1];
    float* out = (float*)d_out;
    float* ws  = (float*)d_ws;

    long long cells = (long long)in_sizes[0] / 16;      // 8192*13*13 = 1384448
    long long half  = (cells + 1) / 2;                  // 692224

    int blocks = (int)((half + 255) / 256);             // 2704 -> one pair per thread
    size_t need = (size_t)blocks * 3 * sizeof(float);
    while (need > ws_size && blocks > 1) { blocks >>= 1; need = (size_t)blocks * 3 * sizeof(float); }

    phobia_partial<<<blocks, 256, 0, stream>>>(pred, tgt, ws, cells, half);
    phobia_final<<<1, 1024, 0, stream>>>(ws, blocks, out, cells);
}

// Round 3
// 32.709 us; speedup vs baseline: 1.5755x; 1.5755x over previous
//
#include <hip/hip_runtime.h>
#include <math.h>

// YOLO-style loss: fused single-pass streaming reduction.
// One cell per thread (grid covers all cells) for max TLP; R1's proven 32-VGPR body.
// cells = N*S*S = 8192*169; pred row = 16 f32 (64B-aligned); tgt row = 13 f32 (4B-aligned only).

#define EPSV 1e-6f

__global__ __launch_bounds__(256) void phobia_partial(
    const float* __restrict__ pred, const float* __restrict__ tgt,
    float* __restrict__ ws, long long cells)
{
    long long idx0 = (long long)blockIdx.x * blockDim.x + threadIdx.x;
    long long stride = (long long)gridDim.x * blockDim.x;

    float accA = 0.f;   // sum m * (5*coord + bce_obj + ce)
    float accB = 0.f;   // sum (1-m) * (bce_noobj4 + bce_noobj9)
    float accC = 0.f;   // sum m

    for (long long i = idx0; i < cells; i += stride) {
        const float* pr = pred + i * 16;
        const float* tr = tgt  + i * 13;

        float4 p03   = *reinterpret_cast<const float4*>(pr);       // 16B-aligned
        float  p4    = pr[4];
        float  p9    = pr[9];
        float2 p1011 = *reinterpret_cast<const float2*>(pr + 10);  // 8B-aligned
        float  p12   = pr[12];

        float t0 = tr[0], t1 = tr[1], t2 = tr[2], t3 = tr[3], t4 = tr[4];
        float t10 = tr[10], t11 = tr[11], t12 = tr[12];

        float m = (t4 > 0.f) ? 1.f : 0.f;

        // coord
        float px = 1.f / (1.f + __expf(-p03.x));
        float py = 1.f / (1.f + __expf(-p03.y));
        float dx = px - t0;
        float dy = py - t1;
        float dw = sqrtf(fabsf(p03.z) + EPSV) - sqrtf(fabsf(t2) + EPSV);
        float dh = sqrtf(fabsf(p03.w) + EPSV) - sqrtf(fabsf(t3) + EPSV);
        float coord = dx*dx + dy*dy + dw*dw + dh*dh;

        // conf ch4: share log1p(exp(-|z|)) between logsig(z) and logsig(-z)
        float l1p4 = __logf(1.f + __expf(-fabsf(p4)));
        float logsig_p4 = fminf(p4, 0.f) - l1p4;
        float logsig_m4 = fminf(-p4, 0.f) - l1p4;
        float bce_obj = -(t4 * logsig_p4 + (1.f - t4) * logsig_m4);
        float bce_no4 = -logsig_m4;
        float bce_no9 = fmaxf(p9, 0.f) + __logf(1.f + __expf(-fabsf(p9)));

        // class CE (first-max argmax of one-hot, stable LSE)
        int tcls = 0; float bt = t10;
        if (t11 > bt) { bt = t11; tcls = 1; }
        if (t12 > bt) { tcls = 2; }
        float lt = (tcls == 0) ? p1011.x : ((tcls == 1) ? p1011.y : p12);
        float mx = fmaxf(p1011.x, fmaxf(p1011.y, p12));
        float lse = mx + __logf(__expf(p1011.x - mx) + __expf(p1011.y - mx) + __expf(p12 - mx));
        float ce = lse - lt;

        accA += m * (5.f * coord + bce_obj + ce);
        accB += (1.f - m) * (bce_no4 + bce_no9);
        accC += m;
    }

    #pragma unroll
    for (int o = 32; o > 0; o >>= 1) {
        accA += __shfl_down(accA, o, 64);
        accB += __shfl_down(accB, o, 64);
        accC += __shfl_down(accC, o, 64);
    }
    __shared__ float sA[4], sB[4], sC[4];
    int wave = threadIdx.x >> 6;
    int lane = threadIdx.x & 63;
    if (lane == 0) { sA[wave] = accA; sB[wave] = accB; sC[wave] = accC; }
    __syncthreads();
    if (threadIdx.x == 0) {
        ws[blockIdx.x * 3 + 0] = sA[0] + sA[1] + sA[2] + sA[3];
        ws[blockIdx.x * 3 + 1] = sB[0] + sB[1] + sB[2] + sB[3];
        ws[blockIdx.x * 3 + 2] = sC[0] + sC[1] + sC[2] + sC[3];
    }
}

__global__ __launch_bounds__(1024) void phobia_final(
    const float* __restrict__ ws, int nblocks, float* __restrict__ out, long long cells)
{
    float a = 0.f, b = 0.f, c = 0.f;
    for (int i = threadIdx.x; i < nblocks; i += 1024) {
        a += ws[i * 3 + 0];
        b += ws[i * 3 + 1];
        c += ws[i * 3 + 2];
    }
    #pragma unroll
    for (int o = 32; o > 0; o >>= 1) {
        a += __shfl_down(a, o, 64);
        b += __shfl_down(b, o, 64);
        c += __shfl_down(c, o, 64);
    }
    __shared__ float sA[16], sB[16], sC[16];
    int wave = threadIdx.x >> 6;
    int lane = threadIdx.x & 63;
    if (lane == 0) { sA[wave] = a; sB[wave] = b; sC[wave] = c; }
    __syncthreads();
    if (threadIdx.x == 0) {
        float A = 0.f, B = 0.f, C = 0.f;
        #pragma unroll
        for (int w = 0; w < 16; ++w) { A += sA[w]; B += sB[w]; C += sC[w]; }
        float batch = (float)(cells / 169);               // N
        float invb = 1.f / batch;
        float div_obj   = (C > 0.f) ? invb : 1.f;
        float div_noobj = (C < (float)cells) ? invb : 1.f;
        out[0] = A * div_obj + 0.5f * B * div_noobj;
    }
}

extern "C" void kernel_launch(void* const* d_in, const int* in_sizes, int n_in,
                              void* d_out, int out_size, void* d_ws, size_t ws_size,
                              hipStream_t stream) {
    const float* pred = (const float*)d_in[0];
    const float* tgt  = (const float*)d_in[1];
    float* out = (float*)d_out;
    float* ws  = (float*)d_ws;

    long long cells = (long long)in_sizes[0] / 16;      // 8192*13*13 = 1384448

    int blocks = (int)((cells + 255) / 256);            // 5408 -> exactly 1 cell/thread
    size_t need = (size_t)blocks * 3 * sizeof(float);
    while (need > ws_size && blocks > 1) { blocks >>= 1; need = (size_t)blocks * 3 * sizeof(float); }

    phobia_partial<<<blocks, 256, 0, stream>>>(pred, tgt, ws, cells);
    phobia_final<<<1, 1024, 0, stream>>>(ws, blocks, out, cells);
}